// Round 14
// baseline (456.474 us; speedup 1.0000x reference)
//
#include <hip/hip_runtime.h>
#include <math.h>

#define NT   512    // 8 waves/block, 1 block/CU -> 2 waves/SIMD (VGPR cap 256)
#define BR   32
#define TAU  1e-3f
#define LIST_CAP 65536

typedef _Float16 half8 __attribute__((ext_vector_type(8)));
typedef float    f32x4 __attribute__((ext_vector_type(4)));
typedef unsigned int u32x4 __attribute__((ext_vector_type(4)));

#define SWZ(r) (((r)&7)<<4)

// ---------- workspace layout ----------
#define PACK_ELS 425984            // L1 262144 + L2 131072 + L3 32768 (f16 each)
#define OFF_LIST 16
#define OFF_PH   (16 + LIST_CAP*4)
#define OFF_PL   (OFF_PH + PACK_ELS*2)
#define WS_PACK_NEED (OFF_PL + PACK_ELS*2)         // ~1.87 MB
#define WS_F32_NEED  (16 + LIST_CAP*4)

// legacy permutations for the f32/f64 fallback path (verified R2/R3)
__device__ __forceinline__ int p1(int c){ return ((c&7)<<6)|(c>>3); }
__device__ __forceinline__ int p2(int c){ return ((c&3)<<6)|(c>>2); }
__device__ __forceinline__ int p3(int c){ return ((c&1)<<6)|(c>>1); }

// ============ weight pack (R11 version: coalesced writes) ===================
// idx (((nt*KS + ks)*64 + lane)*8 + j) holds W[ks*32+(lane>>4)*8+j][nt*16+(lane&15)]
__global__ void pack_w(const float* __restrict__ W1, const float* __restrict__ W2,
                       const float* __restrict__ W3,
                       _Float16* __restrict__ PH, _Float16* __restrict__ PL) {
    int i = blockIdx.x * 256 + threadIdx.x;
    if (i >= PACK_ELS) return;
    const float* W; int N, KS, loc;
    if (i < 262144)            { W = W1; N = 512; KS = 16; loc = i; }
    else if (i < 393216)       { W = W2; N = 256; KS = 16; loc = i - 262144; }
    else                       { W = W3; N = 128; KS = 8;  loc = i - 393216; }
    int j   = loc & 7;
    int l   = (loc >> 3) & 63;
    int rest = loc >> 9;
    int ks  = rest & (KS - 1);
    int nt  = rest >> (KS == 16 ? 4 : 3);
    int k = ks * 32 + (l >> 4) * 8 + j;
    int n = nt * 16 + (l & 15);
    float v = W[k * N + n];
    _Float16 hi = (_Float16)v;
    _Float16 lo = (_Float16)(v - (float)hi);
    PH[i] = hi; PL[i] = lo;
}

// ============ asm load + counted-vmcnt primitives ===========================
__device__ __forceinline__ u32x4 agl(const _Float16* p) {
    u32x4 d;
    asm volatile("global_load_dwordx4 %0, %1, off" : "=v"(d) : "v"(p));
    return d;
}
template<int NWAIT> __device__ __forceinline__ void waitv() {
    if constexpr (NWAIT == 0)       asm volatile("s_waitcnt vmcnt(0)");
    else if constexpr (NWAIT == 2)  asm volatile("s_waitcnt vmcnt(2)");
    else if constexpr (NWAIT == 4)  asm volatile("s_waitcnt vmcnt(4)");
    else if constexpr (NWAIT == 6)  asm volatile("s_waitcnt vmcnt(6)");
    else if constexpr (NWAIT == 8)  asm volatile("s_waitcnt vmcnt(8)");
    else if constexpr (NWAIT == 12) asm volatile("s_waitcnt vmcnt(12)");
    else if constexpr (NWAIT == 16) asm volatile("s_waitcnt vmcnt(16)");
    else                            asm volatile("s_waitcnt vmcnt(24)");
    __builtin_amdgcn_sched_barrier(0);   // rule #18: no MFMA hoist above the wait
}

// ============ MFMA layer: asm B pipeline (distance 3) + A prefetch ==========
// 8 waves; wave covers NTW n-tiles x MREP m-tiles at (nt0, m0); B read exactly
// once per block. actIn split f16 [row][k], hi at 0, lo at +BR*K*2, XOR-swz.
// 3-term f16 split. B via volatile-asm global_load_dwordx4 into a 4-slot
// rotation, counted vmcnt (FIFO, m135): min(3, rem)*BATCH. A prefetched 1 ks
// ahead in compiler-tracked regs (counted lgkmcnt auto-emitted).
template<int K, int N, int NTW, int MREP, bool SPLIT_OUT>
__device__ __forceinline__ void mfma_layer(const char* __restrict__ actIn,
    const _Float16* __restrict__ PH, const _Float16* __restrict__ PL,
    const float* __restrict__ bias,
    char* __restrict__ actOut, float* __restrict__ h3out,
    int nt0, int m0, int l)
{
    constexpr int KS    = K / 32;
    constexpr int BATCH = 2 * NTW;        // asm loads per ks batch (hi+lo per tile)
    const int r  = l & 15;
    const int kg = l >> 4;
    f32x4 acc[MREP][NTW];
#pragma unroll
    for (int t = 0; t < NTW; ++t) {
        float bb = bias[(nt0 + t) * 16 + r];
#pragma unroll
        for (int m = 0; m < MREP; ++m) acc[m][t] = (f32x4){bb, bb, bb, bb};
    }
    __builtin_amdgcn_sched_barrier(0);    // bias loads+waits stay above asm region
    constexpr int loIn = BR * K * 2;

#define AADDR(m, ks) ((((((m0 + (m)) * 16 + r) * K + kg * 8 + (ks) * 32) * 2) ^ SWZ((m0 + (m)) * 16 + r)))
#define BOFF(t, ks)  (((size_t)((nt0 + (t)) * KS + (ks)) * 64 + l) * 8)

    u32x4 Bh[4][NTW], Bl[4][NTW];
#pragma unroll
    for (int p = 0; p < 3; ++p) {
        if (p < KS) {
#pragma unroll
            for (int t = 0; t < NTW; ++t) {
                Bh[p][t] = agl(PH + BOFF(t, p));
                Bl[p][t] = agl(PL + BOFF(t, p));
            }
        }
    }
    half8 ah0[MREP], al0[MREP];
#pragma unroll
    for (int m = 0; m < MREP; ++m) {
        int ao = AADDR(m, 0);
        ah0[m] = *(const half8*)(actIn + ao);
        al0[m] = *(const half8*)(actIn + ao + loIn);
    }

#pragma unroll
    for (int ks = 0; ks < KS; ++ks) {
        const int cur = ks & 3, nx = (ks + 3) & 3;
        if (ks + 3 < KS) {
#pragma unroll
            for (int t = 0; t < NTW; ++t) {
                Bh[nx][t] = agl(PH + BOFF(t, ks + 3));
                Bl[nx][t] = agl(PL + BOFF(t, ks + 3));
            }
        }
        half8 ahn[MREP], aln[MREP];
        if (ks + 1 < KS) {
#pragma unroll
            for (int m = 0; m < MREP; ++m) {
                int ao = AADDR(m, ks + 1);
                ahn[m] = *(const half8*)(actIn + ao);
                aln[m] = *(const half8*)(actIn + ao + loIn);
            }
        }
        const int rem = KS - 1 - ks;      // batches issued after this one
        if (rem >= 3)      waitv<3 * BATCH>();
        else if (rem == 2) waitv<2 * BATCH>();
        else if (rem == 1) waitv<BATCH>();
        else               waitv<0>();
        __builtin_amdgcn_s_setprio(1);
#pragma unroll
        for (int t = 0; t < NTW; ++t) {
            half8 bh = __builtin_bit_cast(half8, Bh[cur][t]);
            half8 bl = __builtin_bit_cast(half8, Bl[cur][t]);
#pragma unroll
            for (int m = 0; m < MREP; ++m) {
                acc[m][t] = __builtin_amdgcn_mfma_f32_16x16x32_f16(ah0[m], bh, acc[m][t], 0, 0, 0);
                acc[m][t] = __builtin_amdgcn_mfma_f32_16x16x32_f16(ah0[m], bl, acc[m][t], 0, 0, 0);
                acc[m][t] = __builtin_amdgcn_mfma_f32_16x16x32_f16(al0[m], bh, acc[m][t], 0, 0, 0);
            }
        }
        __builtin_amdgcn_s_setprio(0);
        __builtin_amdgcn_sched_barrier(0);
#pragma unroll
        for (int m = 0; m < MREP; ++m) { ah0[m] = ahn[m]; al0[m] = aln[m]; }
    }
#undef AADDR
#undef BOFF

    constexpr int loOut = BR * N * 2;
#pragma unroll
    for (int t = 0; t < NTW; ++t) {
        int n = (nt0 + t) * 16 + r;
#pragma unroll
        for (int m = 0; m < MREP; ++m)
#pragma unroll
        for (int b = 0; b < 4; ++b) {
            int rowD = (m0 + m) * 16 + kg * 4 + b;
            float v = acc[m][t][b];
            v = v > 0.f ? v : 0.f;
            if constexpr (SPLIT_OUT) {
                _Float16 hi = (_Float16)v;
                _Float16 lo = (_Float16)(v - (float)hi);
                int lin = (rowD * N + n) * 2;
                int sw  = lin ^ SWZ(rowD);
                *(_Float16*)(actOut + sw)         = hi;
                *(_Float16*)(actOut + sw + loOut) = lo;
            } else {
                h3out[rowD * 132 + n] = v;
            }
        }
    }
}

// ============ pass 1: fused MLP via f16-split MFMA + flagging ===============
__global__ __launch_bounds__(NT, 2)
void dec_mfma(const float* __restrict__ z,
              const float* __restrict__ b1, const float* __restrict__ b2,
              const float* __restrict__ b3,
              const float* __restrict__ W4, const float* __restrict__ b4,
              const float* __restrict__ adj,
              const _Float16* __restrict__ PH, const _Float16* __restrict__ PL,
              float* __restrict__ out, int B,
              int* __restrict__ cnt, int* __restrict__ list)
{
    __shared__ __align__(16) char ldsA[65536];   // z / h2 (hi+lo planes)
    __shared__ __align__(16) char ldsB[65536];   // h1 (hi+lo); then h3 f32
    __shared__ float logitsS[BR * 20];
    __shared__ float maskS[BR * 20];
    __shared__ float adjS[400];

    const int tid = threadIdx.x;
    const int w   = tid >> 6;      // wave 0..7
    const int l   = tid & 63;
    const int rowBase = blockIdx.x * BR;

    const int O_MASK  = B * 400;
    const int O_PROBS = O_MASK + B * 20;
    const int O_LOSS  = O_PROBS + B * 20;

    if (tid < 400) adjS[tid] = adj[tid];

    // ---- stage z: 16-float chunks, vectorized float4 reads, split hi/lo ----
#pragma unroll
    for (int i = tid; i < BR * 32; i += NT) {
        int r   = i >> 5;
        int c16 = (i & 31) * 16;
        const float4* zp = (const float4*)(z + (size_t)(rowBase + r) * 512 + c16);
        float4 f0 = zp[0], f1 = zp[1], f2 = zp[2], f3 = zp[3];
        float fv[16] = {f0.x,f0.y,f0.z,f0.w, f1.x,f1.y,f1.z,f1.w,
                        f2.x,f2.y,f2.z,f2.w, f3.x,f3.y,f3.z,f3.w};
        half8 hi0, hi1, lo0, lo1;
#pragma unroll
        for (int j = 0; j < 8; ++j) {
            _Float16 h = (_Float16)fv[j];
            hi0[j] = h; lo0[j] = (_Float16)(fv[j] - (float)h);
        }
#pragma unroll
        for (int j = 0; j < 8; ++j) {
            _Float16 h = (_Float16)fv[8 + j];
            hi1[j] = h; lo1[j] = (_Float16)(fv[8 + j] - (float)h);
        }
        int lin = (r * 512 + c16) * 2;
        int swz = SWZ(r);
        *(half8*)(ldsA + ((lin     ) ^ swz))          = hi0;
        *(half8*)(ldsA + ((lin + 16) ^ swz))          = hi1;
        *(half8*)(ldsA + ((lin     ) ^ swz) + 32768)  = lo0;
        *(half8*)(ldsA + ((lin + 16) ^ swz) + 32768)  = lo1;
    }
    __syncthreads();

    // L1: 512->512. 8 waves x (4 n-tiles, 2 m-tiles) -> B read once
    mfma_layer<512, 512, 4, 2, true >(ldsA, PH,          PL,          b1, ldsB, nullptr, w * 4, 0, l);
    __syncthreads();
    // L2: 512->256. 8 waves x (2 n-tiles, 2 m-tiles)
    mfma_layer<512, 256, 2, 2, true >(ldsB, PH + 262144, PL + 262144, b2, ldsA, nullptr, w * 2, 0, l);
    __syncthreads();
    // L3: 256->128. 8 waves x (1 n-tile, 2 m-tiles)
    mfma_layer<256, 128, 1, 2, false>(ldsA, PH + 393216, PL + 393216, b3, nullptr, (float*)ldsB, w, 0, l);
    __syncthreads();

    // L4: 128 -> 20 logits, vector f32
    const float* h3 = (const float*)ldsB;
    for (int o = tid; o < BR * 20; o += NT) {
        int r = o / 20, c = o - r * 20;
        float acc = b4[c];
        for (int k = 0; k < 128; ++k)
            acc += h3[r * 132 + k] * W4[k * 20 + c];
        logitsS[o] = acc;
    }
    __syncthreads();

    // flag rows whose mask could flip under split-f16 rounding
    if (tid < BR) {
        float mn = 1e30f;
#pragma unroll
        for (int c = 0; c < 20; ++c)
            mn = fminf(mn, fabsf(logitsS[tid * 20 + c]));
        if (mn < TAU) {
            int idx = atomicAdd(cnt, 1);
            if (idx < LIST_CAP) list[idx] = rowBase + tid;
        }
    }

    // epilogue
    for (int o = tid; o < BR * 20; o += NT) {
        double lg = (double)logitsS[o];
        double p  = 1.0 / (1.0 + exp(-lg));
        out[O_PROBS + rowBase * 20 + o] = (float)p;
        float m = lg > 0.0 ? 1.0f : 0.0f;
        out[O_MASK + rowBase * 20 + o] = m;
        maskS[o] = m;
    }
    __syncthreads();

    for (int o = tid; o < BR * 20; o += NT) {
        int r = o / 20, ii = o - r * 20;
        float mri = maskS[r * 20 + ii];
        float* orow = &out[(rowBase + r) * 400 + ii * 20];
#pragma unroll
        for (int b = 0; b < 5; ++b) {
            float4 v;
            v.x = mri * maskS[r * 20 + 4*b+0] * adjS[ii * 20 + 4*b+0];
            v.y = mri * maskS[r * 20 + 4*b+1] * adjS[ii * 20 + 4*b+1];
            v.z = mri * maskS[r * 20 + 4*b+2] * adjS[ii * 20 + 4*b+2];
            v.w = mri * maskS[r * 20 + 4*b+3] * adjS[ii * 20 + 4*b+3];
            *(float4*)&orow[4*b] = v;
        }
    }

    if (blockIdx.x == 0 && tid == 0) out[O_LOSS] = 0.0f;
}

// ============ fallback: fused f32/f64 vector kernel (R7, proven) ============
template<typename T, bool FLAG>
__global__ __launch_bounds__(256, 2)
void dec_fused(const float* __restrict__ z,
               const float* __restrict__ W1, const float* __restrict__ b1,
               const float* __restrict__ W2, const float* __restrict__ b2,
               const float* __restrict__ W3, const float* __restrict__ b3,
               const float* __restrict__ W4, const float* __restrict__ b4,
               const float* __restrict__ adj,
               float* __restrict__ out, int B,
               int* __restrict__ cnt, int* __restrict__ list)
{
    constexpr int STR = (sizeof(T) == 4) ? 20 : 17;
    __shared__ T     hT[512 * STR];
    __shared__ T     logitsS[16 * 20];
    __shared__ float maskS[16 * 20];
    __shared__ float adjS[400];

    const int tid = threadIdx.x;
    const int rg  = tid >> 6;
    const int cg  = tid & 63;
    const int r0  = rg * 4;
    const int rowBase = blockIdx.x * 16;

    const int O_MASK  = B * 400;
    const int O_PROBS = O_MASK + B * 20;
    const int O_LOSS  = O_PROBS + B * 20;

    for (int i = tid; i < 400; i += 256) adjS[i] = adj[i];
    for (int i = tid; i < 512 * 16; i += 256) {
        int k = i & 511, r = i >> 9;
        hT[k * STR + r] = (T)z[(rowBase + r) * 512 + k];
    }
    __syncthreads();
    {
        T a[4][8];
#pragma unroll
        for (int ri = 0; ri < 4; ++ri)
#pragma unroll
            for (int ci = 0; ci < 8; ++ci) a[ri][ci] = (T)0;
#pragma unroll 2
        for (int k = 0; k < 512; ++k) {
            T zr[4];
#pragma unroll
            for (int ri = 0; ri < 4; ++ri) zr[ri] = hT[k * STR + r0 + ri];
            const float4* w1p = (const float4*)(W1 + k * 512 + cg * 8);
            float4 w0 = w1p[0], w1v = w1p[1];
            T wv[8] = {(T)w0.x,(T)w0.y,(T)w0.z,(T)w0.w,
                       (T)w1v.x,(T)w1v.y,(T)w1v.z,(T)w1v.w};
#pragma unroll
            for (int ci = 0; ci < 8; ++ci)
#pragma unroll
                for (int ri = 0; ri < 4; ++ri)
                    a[ri][ci] += zr[ri] * wv[ci];
        }
        __syncthreads();
#pragma unroll
        for (int ci = 0; ci < 8; ++ci) {
            int c = cg * 8 + ci;
            T bb = (T)b1[c]; int cp = p1(c);
#pragma unroll
            for (int ri = 0; ri < 4; ++ri) {
                T v = a[ri][ci] + bb;
                hT[cp * STR + r0 + ri] = v > (T)0 ? v : (T)0;
            }
        }
        __syncthreads();
    }
    {
        T a[4][4];
#pragma unroll
        for (int ri = 0; ri < 4; ++ri)
#pragma unroll
            for (int ci = 0; ci < 4; ++ci) a[ri][ci] = (T)0;
#pragma unroll 2
        for (int k = 0; k < 512; ++k) {
            int kp = p1(k);
            T zr[4];
#pragma unroll
            for (int ri = 0; ri < 4; ++ri) zr[ri] = hT[kp * STR + r0 + ri];
            float4 wq = *(const float4*)(W2 + k * 256 + cg * 4);
            T wv[4] = {(T)wq.x,(T)wq.y,(T)wq.z,(T)wq.w};
#pragma unroll
            for (int ci = 0; ci < 4; ++ci)
#pragma unroll
                for (int ri = 0; ri < 4; ++ri)
                    a[ri][ci] += zr[ri] * wv[ci];
        }
        __syncthreads();
#pragma unroll
        for (int ci = 0; ci < 4; ++ci) {
            int c = cg * 4 + ci;
            T bb = (T)b2[c]; int cp = p2(c);
#pragma unroll
            for (int ri = 0; ri < 4; ++ri) {
                T v = a[ri][ci] + bb;
                hT[cp * STR + r0 + ri] = v > (T)0 ? v : (T)0;
            }
        }
        __syncthreads();
    }
    {
        T a[4][2];
#pragma unroll
        for (int ri = 0; ri < 4; ++ri)
#pragma unroll
            for (int ci = 0; ci < 2; ++ci) a[ri][ci] = (T)0;
#pragma unroll 2
        for (int k = 0; k < 256; ++k) {
            int kp = p2(k);
            T zr[4];
#pragma unroll
            for (int ri = 0; ri < 4; ++ri) zr[ri] = hT[kp * STR + r0 + ri];
            float2 wq = *(const float2*)(W3 + k * 128 + cg * 2);
            T wv[2] = {(T)wq.x,(T)wq.y};
#pragma unroll
            for (int ci = 0; ci < 2; ++ci)
#pragma unroll
                for (int ri = 0; ri < 4; ++ri)
                    a[ri][ci] += zr[ri] * wv[ci];
        }
        __syncthreads();
#pragma unroll
        for (int ci = 0; ci < 2; ++ci) {
            int c = cg * 2 + ci;
            T bb = (T)b3[c]; int cp = p3(c);
#pragma unroll
            for (int ri = 0; ri < 4; ++ri) {
                T v = a[ri][ci] + bb;
                hT[cp * STR + r0 + ri] = v > (T)0 ? v : (T)0;
            }
        }
        __syncthreads();
    }
    for (int o = tid; o < 16 * 20; o += 256) {
        int r = o / 20, c = o - r * 20;
        T acc = (T)b4[c];
        for (int k = 0; k < 128; ++k)
            acc += hT[p3(k) * STR + r] * (T)W4[k * 20 + c];
        logitsS[o] = acc;
    }
    __syncthreads();
    if constexpr (FLAG) {
        if (tid < 16) {
            float mn = 1e30f;
#pragma unroll
            for (int c = 0; c < 20; ++c)
                mn = fminf(mn, fabsf((float)logitsS[tid * 20 + c]));
            if (mn < TAU) {
                int idx = atomicAdd(cnt, 1);
                if (idx < LIST_CAP) list[idx] = rowBase + tid;
            }
        }
    }
    for (int o = tid; o < 16 * 20; o += 256) {
        double lg = (double)logitsS[o];
        double p  = 1.0 / (1.0 + exp(-lg));
        out[O_PROBS + rowBase * 20 + o] = (float)p;
        float m = lg > 0.0 ? 1.0f : 0.0f;
        out[O_MASK + rowBase * 20 + o] = m;
        maskS[o] = m;
    }
    __syncthreads();
    for (int o = tid; o < 16 * 20; o += 256) {
        int r = o / 20, ii = o - r * 20;
        float mri = maskS[r * 20 + ii];
        float* orow = &out[(rowBase + r) * 400 + ii * 20];
#pragma unroll
        for (int b = 0; b < 5; ++b) {
            float4 v;
            v.x = mri * maskS[r * 20 + 4*b+0] * adjS[ii * 20 + 4*b+0];
            v.y = mri * maskS[r * 20 + 4*b+1] * adjS[ii * 20 + 4*b+1];
            v.z = mri * maskS[r * 20 + 4*b+2] * adjS[ii * 20 + 4*b+2];
            v.w = mri * maskS[r * 20 + 4*b+3] * adjS[ii * 20 + 4*b+3];
            *(float4*)&orow[4*b] = v;
        }
    }
    if (blockIdx.x == 0 && tid == 0) out[O_LOSS] = 0.0f;
}

// ============ exact f64 repair of flagged rows (R7, proven) =================
__global__ __launch_bounds__(256, 4)
void repair_rows(const float* __restrict__ z,
                 const float* __restrict__ W1, const float* __restrict__ b1,
                 const float* __restrict__ W2, const float* __restrict__ b2,
                 const float* __restrict__ W3, const float* __restrict__ b3,
                 const float* __restrict__ W4, const float* __restrict__ b4,
                 const float* __restrict__ adj,
                 float* __restrict__ out, int B,
                 const int* __restrict__ cnt, const int* __restrict__ list)
{
    __shared__ double bufA[512];
    __shared__ double bufB[512];
    __shared__ double lgS[20];
    __shared__ float  mskS[20];

    const int tid = threadIdx.x;
    const int O_MASK  = B * 400;
    const int O_PROBS = O_MASK + B * 20;

    int n = *cnt;
    if (n > LIST_CAP) n = LIST_CAP;

    for (int i = blockIdx.x; i < n; i += gridDim.x) {
        int row = list[i];
        for (int k = tid; k < 512; k += 256)
            bufA[k] = (double)z[(size_t)row * 512 + k];
        __syncthreads();
        {
            int c0 = tid, c1 = tid + 256;
            double a0 = (double)b1[c0], a1 = (double)b1[c1];
            for (int k = 0; k < 512; ++k) {
                double h = bufA[k];
                a0 += h * (double)W1[k * 512 + c0];
                a1 += h * (double)W1[k * 512 + c1];
            }
            __syncthreads();
            bufB[c0] = a0 > 0.0 ? a0 : 0.0;
            bufB[c1] = a1 > 0.0 ? a1 : 0.0;
            __syncthreads();
        }
        {
            double a0 = (double)b2[tid < 256 ? tid : 0];
            if (tid < 256)
                for (int k = 0; k < 512; ++k)
                    a0 += bufB[k] * (double)W2[k * 256 + tid];
            __syncthreads();
            if (tid < 256) bufA[tid] = a0 > 0.0 ? a0 : 0.0;
            __syncthreads();
        }
        {
            double a0 = (double)b3[tid < 128 ? tid : 0];
            if (tid < 128)
                for (int k = 0; k < 256; ++k)
                    a0 += bufA[k] * (double)W3[k * 128 + tid];
            __syncthreads();
            if (tid < 128) bufB[tid] = a0 > 0.0 ? a0 : 0.0;
            __syncthreads();
        }
        if (tid < 20) {
            double a0 = (double)b4[tid];
            for (int k = 0; k < 128; ++k)
                a0 += bufB[k] * (double)W4[k * 20 + tid];
            lgS[tid] = a0;
        }
        __syncthreads();
        if (tid < 20) {
            double lg = lgS[tid];
            out[O_PROBS + (size_t)row * 20 + tid] = (float)(1.0 / (1.0 + exp(-lg)));
            float m = lg > 0.0 ? 1.0f : 0.0f;
            out[O_MASK + (size_t)row * 20 + tid] = m;
            mskS[tid] = m;
        }
        __syncthreads();
        for (int o = tid; o < 400; o += 256) {
            int ii = o / 20, jj = o - ii * 20;
            out[(size_t)row * 400 + o] = mskS[ii] * mskS[jj] * adj[o];
        }
        __syncthreads();
    }
}

extern "C" void kernel_launch(void* const* d_in, const int* in_sizes, int n_in,
                              void* d_out, int out_size, void* d_ws, size_t ws_size,
                              hipStream_t stream) {
    const float* z   = (const float*)d_in[0];
    const float* W1  = (const float*)d_in[1];
    const float* b1  = (const float*)d_in[2];
    const float* W2  = (const float*)d_in[3];
    const float* b2  = (const float*)d_in[4];
    const float* W3  = (const float*)d_in[5];
    const float* b3  = (const float*)d_in[6];
    const float* W4  = (const float*)d_in[7];
    const float* b4  = (const float*)d_in[8];
    const float* adj = (const float*)d_in[9];
    float* out = (float*)d_out;

    const int B = in_sizes[0] / 512;   // 65536

    if (ws_size >= (size_t)WS_PACK_NEED) {
        int* cnt  = (int*)d_ws;
        int* list = (int*)((char*)d_ws + OFF_LIST);
        _Float16* PH = (_Float16*)((char*)d_ws + OFF_PH);
        _Float16* PL = (_Float16*)((char*)d_ws + OFF_PL);
        hipMemsetAsync(d_ws, 0, 16, stream);
        hipLaunchKernelGGL(pack_w, dim3((PACK_ELS + 255) / 256), dim3(256), 0, stream,
                           W1, W2, W3, PH, PL);
        hipLaunchKernelGGL(dec_mfma, dim3(B / BR), dim3(NT), 0, stream,
                           z, b1, b2, b3, W4, b4, adj, PH, PL, out, B, cnt, list);
        hipLaunchKernelGGL(repair_rows, dim3(1024), dim3(256), 0, stream,
                           z, W1, b1, W2, b2, W3, b3, W4, b4, adj, out, B, cnt, list);
    } else if (ws_size >= (size_t)WS_F32_NEED) {
        int* cnt  = (int*)d_ws;
        int* list = (int*)((char*)d_ws + OFF_LIST);
        hipMemsetAsync(d_ws, 0, 16, stream);
        hipLaunchKernelGGL((dec_fused<float, true>), dim3(B / 16), dim3(256), 0, stream,
                           z, W1, b1, W2, b2, W3, b3, W4, b4, adj, out, B, cnt, list);
        hipLaunchKernelGGL(repair_rows, dim3(1024), dim3(256), 0, stream,
                           z, W1, b1, W2, b2, W3, b3, W4, b4, adj, out, B, cnt, list);
    } else {
        hipLaunchKernelGGL((dec_fused<double, false>), dim3(B / 16), dim3(256), 0, stream,
                           z, W1, b1, W2, b2, W3, b3, W4, b4, adj, out, B,
                           (int*)nullptr, (int*)nullptr);
    }
}

// Round 15
// 424.554 us; speedup vs baseline: 1.0752x; 1.0752x over previous
//
#include <hip/hip_runtime.h>
#include <math.h>

#define NT   1024   // dec_mfma: 16 waves/block, 1 block/CU -> 4 waves/SIMD (R13 best)
#define BR   32
#define TAU  1e-3f
#define LIST_CAP 65536
#define RPB  8      // repair rows per weight pass

typedef _Float16 half8 __attribute__((ext_vector_type(8)));
typedef float    f32x4 __attribute__((ext_vector_type(4)));
typedef unsigned int u32x4 __attribute__((ext_vector_type(4)));

#define SWZ(r) (((r)&7)<<4)

// ---------- workspace layout ----------
#define PACK_ELS 425984            // L1 262144 + L2 131072 + L3 32768 (f16 each)
#define OFF_LIST 16
#define OFF_PH   (16 + LIST_CAP*4)
#define OFF_PL   (OFF_PH + PACK_ELS*2)
#define OFF_W4T  (OFF_PL + PACK_ELS*2)
#define WS_PACK_NEED (OFF_W4T + 2560*4)            // ~1.89 MB
#define WS_F32_NEED  (16 + LIST_CAP*4)

// legacy permutations for the f32/f64 fallback path (verified R2/R3)
__device__ __forceinline__ int p1(int c){ return ((c&7)<<6)|(c>>3); }
__device__ __forceinline__ int p2(int c){ return ((c&3)<<6)|(c>>2); }
__device__ __forceinline__ int p3(int c){ return ((c&1)<<6)|(c>>1); }

// ============ weight pack + W4 transpose + counter zero =====================
// Pack idx (((nt*KS + ks)*64 + lane)*8 + j) holds W[ks*32+(lane>>4)*8+j][nt*16+(lane&15)]
__global__ void pack_w(const float* __restrict__ W1, const float* __restrict__ W2,
                       const float* __restrict__ W3, const float* __restrict__ W4,
                       _Float16* __restrict__ PH, _Float16* __restrict__ PL,
                       float* __restrict__ W4T, int* __restrict__ cnt) {
    int i = blockIdx.x * 256 + threadIdx.x;
    if (i == 0) *cnt = 0;                       // replaces the memset dispatch
    if (i >= PACK_ELS) {
        int t = i - PACK_ELS;
        if (t < 2560) {                          // W4T[c][k] = W4[k][c]
            int c = t >> 7, k = t & 127;
            W4T[c * 128 + k] = W4[k * 20 + c];
        }
        return;
    }
    const float* W; int N, KS, loc;
    if (i < 262144)            { W = W1; N = 512; KS = 16; loc = i; }
    else if (i < 393216)       { W = W2; N = 256; KS = 16; loc = i - 262144; }
    else                       { W = W3; N = 128; KS = 8;  loc = i - 393216; }
    int j   = loc & 7;
    int l   = (loc >> 3) & 63;
    int rest = loc >> 9;
    int ks  = rest & (KS - 1);
    int nt  = rest >> (KS == 16 ? 4 : 3);
    int k = ks * 32 + (l >> 4) * 8 + j;
    int n = nt * 16 + (l & 15);
    float v = W[k * N + n];
    _Float16 hi = (_Float16)v;
    _Float16 lo = (_Float16)(v - (float)hi);
    PH[i] = hi; PL[i] = lo;
}

// ============ asm load + counted-vmcnt primitives ===========================
__device__ __forceinline__ u32x4 agl(const _Float16* p) {
    u32x4 d;
    asm volatile("global_load_dwordx4 %0, %1, off" : "=v"(d) : "v"(p));
    return d;
}
template<int NWAIT> __device__ __forceinline__ void waitv() {
    if constexpr (NWAIT == 0)      asm volatile("s_waitcnt vmcnt(0)");
    else if constexpr (NWAIT == 2) asm volatile("s_waitcnt vmcnt(2)");
    else if constexpr (NWAIT == 4) asm volatile("s_waitcnt vmcnt(4)");
    else                           asm volatile("s_waitcnt vmcnt(8)");
    __builtin_amdgcn_sched_barrier(0);   // rule #18: no MFMA hoist above the wait
}

// ============ MFMA layer: asm B pipeline at distance 2 (R13, best) ==========
template<int K, int N, int NTW, int MREP, bool SPLIT_OUT>
__device__ __forceinline__ void mfma_layer(const char* __restrict__ actIn,
    const _Float16* __restrict__ PH, const _Float16* __restrict__ PL,
    const float* __restrict__ bias,
    char* __restrict__ actOut, float* __restrict__ h3out,
    int nt0, int m0, int l)
{
    constexpr int KS    = K / 32;
    constexpr int BATCH = 2 * NTW;        // asm loads per ks batch (hi+lo per tile)
    const int r  = l & 15;
    const int kg = l >> 4;
    f32x4 acc[MREP][NTW];
#pragma unroll
    for (int t = 0; t < NTW; ++t) {
        float bb = bias[(nt0 + t) * 16 + r];
#pragma unroll
        for (int m = 0; m < MREP; ++m) acc[m][t] = (f32x4){bb, bb, bb, bb};
    }
    __builtin_amdgcn_sched_barrier(0);    // bias loads+waits stay above asm region
    constexpr int loIn = BR * K * 2;

#define AADDR(m, ks) ((((((m0 + (m)) * 16 + r) * K + kg * 8 + (ks) * 32) * 2) ^ SWZ((m0 + (m)) * 16 + r)))
#define BOFF(t, ks)  (((size_t)((nt0 + (t)) * KS + (ks)) * 64 + l) * 8)

    u32x4 Bh[3][NTW], Bl[3][NTW];
#pragma unroll
    for (int t = 0; t < NTW; ++t) { Bh[0][t] = agl(PH + BOFF(t, 0)); Bl[0][t] = agl(PL + BOFF(t, 0)); }
#pragma unroll
    for (int t = 0; t < NTW; ++t) { Bh[1][t] = agl(PH + BOFF(t, 1)); Bl[1][t] = agl(PL + BOFF(t, 1)); }

#pragma unroll
    for (int ks = 0; ks < KS; ++ks) {
        const int cur = ks % 3, nx = (ks + 2) % 3;
        if (ks + 2 < KS) {
#pragma unroll
            for (int t = 0; t < NTW; ++t) {
                Bh[nx][t] = agl(PH + BOFF(t, ks + 2));
                Bl[nx][t] = agl(PL + BOFF(t, ks + 2));
            }
        }
        half8 ah[MREP], al[MREP];
#pragma unroll
        for (int m = 0; m < MREP; ++m) {
            int ao = AADDR(m, ks);
            ah[m] = *(const half8*)(actIn + ao);
            al[m] = *(const half8*)(actIn + ao + loIn);
        }
        const int rem = KS - 1 - ks;      // batches issued after this one
        if (rem >= 2)      waitv<2 * BATCH>();
        else if (rem == 1) waitv<BATCH>();
        else               waitv<0>();
        __builtin_amdgcn_s_setprio(1);
#pragma unroll
        for (int t = 0; t < NTW; ++t) {
            half8 bh = __builtin_bit_cast(half8, Bh[cur][t]);
            half8 bl = __builtin_bit_cast(half8, Bl[cur][t]);
#pragma unroll
            for (int m = 0; m < MREP; ++m) {
                acc[m][t] = __builtin_amdgcn_mfma_f32_16x16x32_f16(ah[m], bh, acc[m][t], 0, 0, 0);
                acc[m][t] = __builtin_amdgcn_mfma_f32_16x16x32_f16(ah[m], bl, acc[m][t], 0, 0, 0);
                acc[m][t] = __builtin_amdgcn_mfma_f32_16x16x32_f16(al[m], bh, acc[m][t], 0, 0, 0);
            }
        }
        __builtin_amdgcn_s_setprio(0);
        __builtin_amdgcn_sched_barrier(0);
    }
#undef AADDR
#undef BOFF

    constexpr int loOut = BR * N * 2;
#pragma unroll
    for (int t = 0; t < NTW; ++t) {
        int n = (nt0 + t) * 16 + r;
#pragma unroll
        for (int m = 0; m < MREP; ++m)
#pragma unroll
        for (int b = 0; b < 4; ++b) {
            int rowD = (m0 + m) * 16 + kg * 4 + b;
            float v = acc[m][t][b];
            v = v > 0.f ? v : 0.f;
            if constexpr (SPLIT_OUT) {
                _Float16 hi = (_Float16)v;
                _Float16 lo = (_Float16)(v - (float)hi);
                int lin = (rowD * N + n) * 2;
                int sw  = lin ^ SWZ(rowD);
                *(_Float16*)(actOut + sw)         = hi;
                *(_Float16*)(actOut + sw + loOut) = lo;
            } else {
                h3out[rowD * 132 + n] = v;
            }
        }
    }
}

// ============ pass 1: fused MLP via f16-split MFMA + flagging ===============
__global__ __launch_bounds__(NT, 4)
void dec_mfma(const float* __restrict__ z,
              const float* __restrict__ b1, const float* __restrict__ b2,
              const float* __restrict__ b3,
              const float* __restrict__ W4T, const float* __restrict__ b4,
              const float* __restrict__ adj,
              const _Float16* __restrict__ PH, const _Float16* __restrict__ PL,
              float* __restrict__ out, int B,
              int* __restrict__ cnt, int* __restrict__ list)
{
    __shared__ __align__(16) char ldsA[65536];   // z / h2 (hi+lo planes)
    __shared__ __align__(16) char ldsB[65536];   // h1 (hi+lo); then h3 f32
    __shared__ float logitsS[BR * 20];
    __shared__ float maskS[BR * 20];
    __shared__ float adjS[400];

    const int tid = threadIdx.x;
    const int w   = tid >> 6;      // wave 0..15
    const int l   = tid & 63;
    const int rowBase = blockIdx.x * BR;

    const int O_MASK  = B * 400;
    const int O_PROBS = O_MASK + B * 20;
    const int O_LOSS  = O_PROBS + B * 20;

    if (tid < 400) adjS[tid] = adj[tid];

    // ---- stage z: one 16-float chunk per thread, vectorized float4 reads ----
    {
        int r   = tid >> 5;              // 32 rows
        int c16 = (tid & 31) * 16;       // 32 chunks of 16 k
        const float4* zp = (const float4*)(z + (size_t)(rowBase + r) * 512 + c16);
        float4 f0 = zp[0], f1 = zp[1], f2 = zp[2], f3 = zp[3];
        float fv[16] = {f0.x,f0.y,f0.z,f0.w, f1.x,f1.y,f1.z,f1.w,
                        f2.x,f2.y,f2.z,f2.w, f3.x,f3.y,f3.z,f3.w};
        half8 hi0, hi1, lo0, lo1;
#pragma unroll
        for (int j = 0; j < 8; ++j) {
            _Float16 h = (_Float16)fv[j];
            hi0[j] = h; lo0[j] = (_Float16)(fv[j] - (float)h);
        }
#pragma unroll
        for (int j = 0; j < 8; ++j) {
            _Float16 h = (_Float16)fv[8 + j];
            hi1[j] = h; lo1[j] = (_Float16)(fv[8 + j] - (float)h);
        }
        int lin = (r * 512 + c16) * 2;
        int swz = SWZ(r);
        *(half8*)(ldsA + ((lin     ) ^ swz))          = hi0;
        *(half8*)(ldsA + ((lin + 16) ^ swz))          = hi1;
        *(half8*)(ldsA + ((lin     ) ^ swz) + 32768)  = lo0;
        *(half8*)(ldsA + ((lin + 16) ^ swz) + 32768)  = lo1;
    }
    __syncthreads();

    // L1: 512->512. 16 waves x (2 n-tiles, 2 m-tiles)
    mfma_layer<512, 512, 2, 2, true >(ldsA, PH,          PL,          b1, ldsB, nullptr, w * 2, 0, l);
    __syncthreads();
    // L2: 512->256. 16 waves x (1 n-tile, 2 m-tiles)
    mfma_layer<512, 256, 1, 2, true >(ldsB, PH + 262144, PL + 262144, b2, ldsA, nullptr, w, 0, l);
    __syncthreads();
    // L3: 256->128. 16 waves x (1 n-tile, 1 m-tile): n = w&7, m = w>>3
    mfma_layer<256, 128, 1, 1, false>(ldsA, PH + 393216, PL + 393216, b3, nullptr, (float*)ldsB, w & 7, w >> 3, l);
    __syncthreads();

    // L4: 128 -> 20 logits, float4-vectorized (h3 row-contig, W4T col-contig)
    const float* h3 = (const float*)ldsB;
    for (int o = tid; o < BR * 20; o += NT) {
        int r = o / 20, c = o - r * 20;
        const float4* hp = (const float4*)(h3 + r * 132);
        const float4* wp = (const float4*)(W4T + c * 128);
        f32x4 av = (f32x4){0.f, 0.f, 0.f, 0.f};
#pragma unroll
        for (int kk = 0; kk < 32; ++kk) {
            float4 h = hp[kk], wv = wp[kk];
            av[0] += h.x * wv.x; av[1] += h.y * wv.y;
            av[2] += h.z * wv.z; av[3] += h.w * wv.w;
        }
        logitsS[o] = b4[c] + ((av[0] + av[1]) + (av[2] + av[3]));
    }
    __syncthreads();

    // flag rows whose mask could flip under split-f16 rounding
    if (tid < BR) {
        float mn = 1e30f;
#pragma unroll
        for (int c = 0; c < 20; ++c)
            mn = fminf(mn, fabsf(logitsS[tid * 20 + c]));
        if (mn < TAU) {
            int idx = atomicAdd(cnt, 1);
            if (idx < LIST_CAP) list[idx] = rowBase + tid;
        }
    }

    // epilogue (f32 sigmoid: error ~1e-7 << 0.02 tol; flagged rows repaired f64)
    for (int o = tid; o < BR * 20; o += NT) {
        float lg = logitsS[o];
        out[O_PROBS + rowBase * 20 + o] = 1.0f / (1.0f + __expf(-lg));
        float m = lg > 0.0f ? 1.0f : 0.0f;
        out[O_MASK + rowBase * 20 + o] = m;
        maskS[o] = m;
    }
    __syncthreads();

    for (int o = tid; o < BR * 20; o += NT) {
        int r = o / 20, ii = o - r * 20;
        float mri = maskS[r * 20 + ii];
        float* orow = &out[(rowBase + r) * 400 + ii * 20];
#pragma unroll
        for (int b = 0; b < 5; ++b) {
            float4 v;
            v.x = mri * maskS[r * 20 + 4*b+0] * adjS[ii * 20 + 4*b+0];
            v.y = mri * maskS[r * 20 + 4*b+1] * adjS[ii * 20 + 4*b+1];
            v.z = mri * maskS[r * 20 + 4*b+2] * adjS[ii * 20 + 4*b+2];
            v.w = mri * maskS[r * 20 + 4*b+3] * adjS[ii * 20 + 4*b+3];
            *(float4*)&orow[4*b] = v;
        }
    }

    if (blockIdx.x == 0 && tid == 0) out[O_LOSS] = 0.0f;
}

// ============ fallback: fused f32 vector kernel (R7, proven) ================
template<typename T, bool FLAG>
__global__ __launch_bounds__(256, 2)
void dec_fused(const float* __restrict__ z,
               const float* __restrict__ W1, const float* __restrict__ b1,
               const float* __restrict__ W2, const float* __restrict__ b2,
               const float* __restrict__ W3, const float* __restrict__ b3,
               const float* __restrict__ W4, const float* __restrict__ b4,
               const float* __restrict__ adj,
               float* __restrict__ out, int B,
               int* __restrict__ cnt, int* __restrict__ list)
{
    constexpr int STR = (sizeof(T) == 4) ? 20 : 17;
    __shared__ T     hT[512 * STR];
    __shared__ T     logitsS[16 * 20];
    __shared__ float maskS[16 * 20];
    __shared__ float adjS[400];

    const int tid = threadIdx.x;
    const int rg  = tid >> 6;
    const int cg  = tid & 63;
    const int r0  = rg * 4;
    const int rowBase = blockIdx.x * 16;

    const int O_MASK  = B * 400;
    const int O_PROBS = O_MASK + B * 20;
    const int O_LOSS  = O_PROBS + B * 20;

    for (int i = tid; i < 400; i += 256) adjS[i] = adj[i];
    for (int i = tid; i < 512 * 16; i += 256) {
        int k = i & 511, r = i >> 9;
        hT[k * STR + r] = (T)z[(rowBase + r) * 512 + k];
    }
    __syncthreads();
    {
        T a[4][8];
#pragma unroll
        for (int ri = 0; ri < 4; ++ri)
#pragma unroll
            for (int ci = 0; ci < 8; ++ci) a[ri][ci] = (T)0;
#pragma unroll 2
        for (int k = 0; k < 512; ++k) {
            T zr[4];
#pragma unroll
            for (int ri = 0; ri < 4; ++ri) zr[ri] = hT[k * STR + r0 + ri];
            const float4* w1p = (const float4*)(W1 + k * 512 + cg * 8);
            float4 w0 = w1p[0], w1v = w1p[1];
            T wv[8] = {(T)w0.x,(T)w0.y,(T)w0.z,(T)w0.w,
                       (T)w1v.x,(T)w1v.y,(T)w1v.z,(T)w1v.w};
#pragma unroll
            for (int ci = 0; ci < 8; ++ci)
#pragma unroll
                for (int ri = 0; ri < 4; ++ri)
                    a[ri][ci] += zr[ri] * wv[ci];
        }
        __syncthreads();
#pragma unroll
        for (int ci = 0; ci < 8; ++ci) {
            int c = cg * 8 + ci;
            T bb = (T)b1[c]; int cp = p1(c);
#pragma unroll
            for (int ri = 0; ri < 4; ++ri) {
                T v = a[ri][ci] + bb;
                hT[cp * STR + r0 + ri] = v > (T)0 ? v : (T)0;
            }
        }
        __syncthreads();
    }
    {
        T a[4][4];
#pragma unroll
        for (int ri = 0; ri < 4; ++ri)
#pragma unroll
            for (int ci = 0; ci < 4; ++ci) a[ri][ci] = (T)0;
#pragma unroll 2
        for (int k = 0; k < 512; ++k) {
            int kp = p1(k);
            T zr[4];
#pragma unroll
            for (int ri = 0; ri < 4; ++ri) zr[ri] = hT[kp * STR + r0 + ri];
            float4 wq = *(const float4*)(W2 + k * 256 + cg * 4);
            T wv[4] = {(T)wq.x,(T)wq.y,(T)wq.z,(T)wq.w};
#pragma unroll
            for (int ci = 0; ci < 4; ++ci)
#pragma unroll
                for (int ri = 0; ri < 4; ++ri)
                    a[ri][ci] += zr[ri] * wv[ci];
        }
        __syncthreads();
#pragma unroll
        for (int ci = 0; ci < 4; ++ci) {
            int c = cg * 4 + ci;
            T bb = (T)b2[c]; int cp = p2(c);
#pragma unroll
            for (int ri = 0; ri < 4; ++ri) {
                T v = a[ri][ci] + bb;
                hT[cp * STR + r0 + ri] = v > (T)0 ? v : (T)0;
            }
        }
        __syncthreads();
    }
    {
        T a[4][2];
#pragma unroll
        for (int ri = 0; ri < 4; ++ri)
#pragma unroll
            for (int ci = 0; ci < 2; ++ci) a[ri][ci] = (T)0;
#pragma unroll 2
        for (int k = 0; k < 256; ++k) {
            int kp = p2(k);
            T zr[4];
#pragma unroll
            for (int ri = 0; ri < 4; ++ri) zr[ri] = hT[kp * STR + r0 + ri];
            float2 wq = *(const float2*)(W3 + k * 128 + cg * 2);
            T wv[2] = {(T)wq.x,(T)wq.y};
#pragma unroll
            for (int ci = 0; ci < 2; ++ci)
#pragma unroll
                for (int ri = 0; ri < 4; ++ri)
                    a[ri][ci] += zr[ri] * wv[ci];
        }
        __syncthreads();
#pragma unroll
        for (int ci = 0; ci < 2; ++ci) {
            int c = cg * 2 + ci;
            T bb = (T)b3[c]; int cp = p3(c);
#pragma unroll
            for (int ri = 0; ri < 4; ++ri) {
                T v = a[ri][ci] + bb;
                hT[cp * STR + r0 + ri] = v > (T)0 ? v : (T)0;
            }
        }
        __syncthreads();
    }
    for (int o = tid; o < 16 * 20; o += 256) {
        int r = o / 20, c = o - r * 20;
        T acc = (T)b4[c];
        for (int k = 0; k < 128; ++k)
            acc += hT[p3(k) * STR + r] * (T)W4[k * 20 + c];
        logitsS[o] = acc;
    }
    __syncthreads();
    if constexpr (FLAG) {
        if (tid < 16) {
            float mn = 1e30f;
#pragma unroll
            for (int c = 0; c < 20; ++c)
                mn = fminf(mn, fabsf((float)logitsS[tid * 20 + c]));
            if (mn < TAU) {
                int idx = atomicAdd(cnt, 1);
                if (idx < LIST_CAP) list[idx] = rowBase + tid;
            }
        }
    }
    for (int o = tid; o < 16 * 20; o += 256) {
        double lg = (double)logitsS[o];
        double p  = 1.0 / (1.0 + exp(-lg));
        out[O_PROBS + rowBase * 20 + o] = (float)p;
        float m = lg > 0.0 ? 1.0f : 0.0f;
        out[O_MASK + rowBase * 20 + o] = m;
        maskS[o] = m;
    }
    __syncthreads();
    for (int o = tid; o < 16 * 20; o += 256) {
        int r = o / 20, ii = o - r * 20;
        float mri = maskS[r * 20 + ii];
        float* orow = &out[(rowBase + r) * 400 + ii * 20];
#pragma unroll
        for (int b = 0; b < 5; ++b) {
            float4 v;
            v.x = mri * maskS[r * 20 + 4*b+0] * adjS[ii * 20 + 4*b+0];
            v.y = mri * maskS[r * 20 + 4*b+1] * adjS[ii * 20 + 4*b+1];
            v.z = mri * maskS[r * 20 + 4*b+2] * adjS[ii * 20 + 4*b+2];
            v.w = mri * maskS[r * 20 + 4*b+3] * adjS[ii * 20 + 4*b+3];
            *(float4*)&orow[4*b] = v;
        }
    }
    if (blockIdx.x == 0 && tid == 0) out[O_LOSS] = 0.0f;
}

// ============ exact f64 repair, batched: RPB rows share one weight pass =====
// Same sequential-k f64 math as the proven per-row repair (rounding-identical).
// LDS reads of activations are wave-uniform broadcasts; weight loads coalesced.
__global__ __launch_bounds__(256, 2)
void repair_rows(const float* __restrict__ z,
                 const float* __restrict__ W1, const float* __restrict__ b1,
                 const float* __restrict__ W2, const float* __restrict__ b2,
                 const float* __restrict__ W3, const float* __restrict__ b3,
                 const float* __restrict__ W4, const float* __restrict__ b4,
                 const float* __restrict__ adj,
                 float* __restrict__ out, int B,
                 const int* __restrict__ cnt, const int* __restrict__ list)
{
    __shared__ double zA[RPB][512];   // z, then h2 (cols 0..255)
    __shared__ double hB[RPB][512];   // h1, then h3 (cols 0..127)
    __shared__ double lgS[RPB][20];
    __shared__ float  mskS[RPB][20];

    const int tid = threadIdx.x;
    const int O_MASK  = B * 400;
    const int O_PROBS = O_MASK + B * 20;

    int n = *cnt;
    if (n > LIST_CAP) n = LIST_CAP;
    int nbatch = (n + RPB - 1) / RPB;

    for (int g = blockIdx.x; g < nbatch; g += gridDim.x) {
        int nv = n - g * RPB; if (nv > RPB) nv = RPB;
        int rows[RPB];
#pragma unroll
        for (int j = 0; j < RPB; ++j)
            rows[j] = list[g * RPB + (j < nv ? j : 0)];

        // stage z (8 rows)
        for (int i = tid; i < RPB * 512; i += 256) {
            int j = i >> 9, k = i & 511;
            zA[j][k] = (double)z[(size_t)rows[j] * 512 + k];
        }
        __syncthreads();

        // L1: 512 -> 512. thread owns cols tid, tid+256 x RPB rows.
        {
            int c0 = tid, c1 = tid + 256;
            double a0[RPB], a1[RPB];
#pragma unroll
            for (int j = 0; j < RPB; ++j) { a0[j] = (double)b1[c0]; a1[j] = (double)b1[c1]; }
            for (int k = 0; k < 512; ++k) {
                double w0 = (double)W1[k * 512 + c0];
                double w1 = (double)W1[k * 512 + c1];
#pragma unroll
                for (int j = 0; j < RPB; ++j) {
                    double h = zA[j][k];           // broadcast
                    a0[j] += h * w0;
                    a1[j] += h * w1;
                }
            }
            __syncthreads();                        // all L1 reads of zA done
#pragma unroll
            for (int j = 0; j < RPB; ++j) {
                hB[j][c0] = a0[j] > 0.0 ? a0[j] : 0.0;
                hB[j][c1] = a1[j] > 0.0 ? a1[j] : 0.0;
            }
            __syncthreads();
        }
        // L2: 512 -> 256. thread owns col tid (<256) x RPB rows; h2 -> zA.
        {
            double a0[RPB];
#pragma unroll
            for (int j = 0; j < RPB; ++j) a0[j] = (double)b2[tid < 256 ? tid : 0];
            if (tid < 256) {
                for (int k = 0; k < 512; ++k) {
                    double wv = (double)W2[k * 256 + tid];
#pragma unroll
                    for (int j = 0; j < RPB; ++j) a0[j] += hB[j][k] * wv;
                }
            }
            __syncthreads();
            if (tid < 256) {
#pragma unroll
                for (int j = 0; j < RPB; ++j)
                    zA[j][tid] = a0[j] > 0.0 ? a0[j] : 0.0;
            }
            __syncthreads();
        }
        // L3: 256 -> 128. thread owns col tid (<128) x RPB rows; h3 -> hB.
        {
            double a0[RPB];
#pragma unroll
            for (int j = 0; j < RPB; ++j) a0[j] = (double)b3[tid < 128 ? tid : 0];
            if (tid < 128) {
                for (int k = 0; k < 256; ++k) {
                    double wv = (double)W3[k * 128 + tid];
#pragma unroll
                    for (int j = 0; j < RPB; ++j) a0[j] += zA[j][k] * wv;
                }
            }
            __syncthreads();
            if (tid < 128) {
#pragma unroll
                for (int j = 0; j < RPB; ++j)
                    hB[j][tid] = a0[j] > 0.0 ? a0[j] : 0.0;
            }
            __syncthreads();
        }
        // L4: 128 -> 20. threads 0..159: (j, c) pairs.
        if (tid < RPB * 20) {
            int j = tid / 20, c = tid - j * 20;
            double a0 = (double)b4[c];
            for (int k = 0; k < 128; ++k)
                a0 += hB[j][k] * (double)W4[k * 20 + c];
            lgS[j][c] = a0;
        }
        __syncthreads();

        if (tid < RPB * 20) {
            int j = tid / 20, c = tid - j * 20;
            double lg = lgS[j][c];
            float m = lg > 0.0 ? 1.0f : 0.0f;
            mskS[j][c] = m;
            if (j < nv) {
                size_t row = (size_t)rows[j];
                out[O_PROBS + row * 20 + c] = (float)(1.0 / (1.0 + exp(-lg)));
                out[O_MASK + row * 20 + c] = m;
            }
        }
        __syncthreads();

        for (int i = tid; i < RPB * 400; i += 256) {
            int j = i / 400, e = i - j * 400;
            if (j < nv) {
                int ii = e / 20, jj = e - ii * 20;
                out[(size_t)rows[j] * 400 + e] = mskS[j][ii] * mskS[j][jj] * adj[e];
            }
        }
        __syncthreads();
    }
}

extern "C" void kernel_launch(void* const* d_in, const int* in_sizes, int n_in,
                              void* d_out, int out_size, void* d_ws, size_t ws_size,
                              hipStream_t stream) {
    const float* z   = (const float*)d_in[0];
    const float* W1  = (const float*)d_in[1];
    const float* b1  = (const float*)d_in[2];
    const float* W2  = (const float*)d_in[3];
    const float* b2  = (const float*)d_in[4];
    const float* W3  = (const float*)d_in[5];
    const float* b3  = (const float*)d_in[6];
    const float* W4  = (const float*)d_in[7];
    const float* b4  = (const float*)d_in[8];
    const float* adj = (const float*)d_in[9];
    float* out = (float*)d_out;

    const int B = in_sizes[0] / 512;   // 65536

    if (ws_size >= (size_t)WS_PACK_NEED) {
        int* cnt  = (int*)d_ws;
        int* list = (int*)((char*)d_ws + OFF_LIST);
        _Float16* PH = (_Float16*)((char*)d_ws + OFF_PH);
        _Float16* PL = (_Float16*)((char*)d_ws + OFF_PL);
        float* W4T = (float*)((char*)d_ws + OFF_W4T);
        hipLaunchKernelGGL(pack_w, dim3((PACK_ELS + 2560 + 255) / 256), dim3(256), 0, stream,
                           W1, W2, W3, W4, PH, PL, W4T, cnt);
        hipLaunchKernelGGL(dec_mfma, dim3(B / BR), dim3(NT), 0, stream,
                           z, b1, b2, b3, W4T, b4, adj, PH, PL, out, B, cnt, list);
        hipLaunchKernelGGL(repair_rows, dim3(512), dim3(256), 0, stream,
                           z, W1, b1, W2, b2, W3, b3, W4, b4, adj, out, B, cnt, list);
    } else if (ws_size >= (size_t)WS_F32_NEED) {
        int* cnt  = (int*)d_ws;
        int* list = (int*)((char*)d_ws + OFF_LIST);
        hipMemsetAsync(d_ws, 0, 16, stream);
        hipLaunchKernelGGL((dec_fused<float, true>), dim3(B / 16), dim3(256), 0, stream,
                           z, W1, b1, W2, b2, W3, b3, W4, b4, adj, out, B, cnt, list);
        hipLaunchKernelGGL(repair_rows, dim3(512), dim3(256), 0, stream,
                           z, W1, b1, W2, b2, W3, b3, W4, b4, adj, out, B, cnt, list);
    } else {
        hipLaunchKernelGGL((dec_fused<double, false>), dim3(B / 16), dim3(256), 0, stream,
                           z, W1, b1, W2, b2, W3, b3, W4, b4, adj, out, B,
                           (int*)nullptr, (int*)nullptr);
    }
}